// Round 3
// baseline (813.056 us; speedup 1.0000x reference)
//
#include <hip/hip_runtime.h>

// ---------------------------------------------------------------------------
// MultiHeadPooledSelfAttention on gfx950.
// bf16 cast once -> all matmul stages through one m97-style GEMM-BT kernel
// (128x128 tile, BK=32, global_load_lds width=16, mfma_f32_16x16x32_bf16,
// 4x4 acc/wave). Attention materializes S per 8-head chunk (17.3 MB) to fit
// workspace; stk aliases the K/V buffer. ws use ~211 MB, guarded.
// ---------------------------------------------------------------------------

typedef unsigned short u16;
typedef __attribute__((ext_vector_type(8))) short short8;   // 8 x bf16
typedef __attribute__((ext_vector_type(4))) float floatx4;

__device__ __forceinline__ u16 f2bf(float f) {
  union { float f; unsigned u; } x; x.f = f;
  unsigned r = (x.u + 0x7fffu + ((x.u >> 16) & 1u)) >> 16;
  return (u16)r;
}
__device__ __forceinline__ float bf2f(u16 u) {
  union { unsigned u; float f; } x; x.u = ((unsigned)u) << 16;
  return x.f;
}

__device__ __forceinline__ void gld_lds16(const void* g, void* l) {
  __builtin_amdgcn_global_load_lds(
      (const __attribute__((address_space(1))) void*)g,
      (__attribute__((address_space(3))) void*)l, 16, 0, 0);
}

// ---------------------------------------------------------------------------
struct CvtArgs { const float* src[8]; u16* dst[8]; int n4[8]; };

__global__ __launch_bounds__(256) void cvt_all(CvtArgs a, int total4) {
  int t = blockIdx.x * 256 + threadIdx.x;
  if (t >= total4) return;
#pragma unroll
  for (int s = 0; s < 8; ++s) {
    if (t < a.n4[s]) {
      const float* sp = a.src[s] + (long)t * 4;
      u16* dp = a.dst[s] + (long)t * 4;
      float4 v = *(const float4*)sp;
      dp[0] = f2bf(v.x); dp[1] = f2bf(v.y); dp[2] = f2bf(v.z); dp[3] = f2bf(v.w);
      return;
    }
    t -= a.n4[s];
  }
}

// ---------------------------------------------------------------------------
__global__ __launch_bounds__(256) void emb_kernel(float* __restrict__ e) {
  int t = blockIdx.x * 256 + threadIdx.x;    // < 1024*512
  int c = t & 511, sp = t >> 9;
  int y = sp >> 5, xg = sp & 31;
  int j = c & 127, seg = c >> 7;
  float omega = expf(-(float)j * (9.210340371976184f / 128.f));  // 10000^{-j/128}
  float arg = (float)((seg < 2) ? y : xg) * omega;
  e[t] = (seg & 1) ? cosf(arg) : sinf(arg);
}

// ---------------------------------------------------------------------------
__global__ __launch_bounds__(256) void cls_qk(const u16* __restrict__ Q, const u16* __restrict__ K,
                                              u16* __restrict__ PQ, u16* __restrict__ PK) {
  int t = blockIdx.x * 256 + threadIdx.x;    // < 32*512
  int bn = t >> 9, c = t & 511;
  long o = (long)bn * 1025 * 512 + c;
  PQ[o] = Q[o];
  PK[o] = K[o];
}
__global__ __launch_bounds__(256) void cls_v(const u16* __restrict__ V, u16* __restrict__ PVt) {
  int t = blockIdx.x * 256 + threadIdx.x;
  int bn = t >> 9, c = t & 511;
  PVt[((long)bn * 512 + c) * 1056] = V[(long)bn * 1025 * 512 + c];
}

// ---------------------------------------------------------------------------
// Softmax over a chunk of S: one block per row (8*1025 rows, 1056 cols,
// valid 1025). In-place bf16; zero-fills pad cols 1025..1055.
// ---------------------------------------------------------------------------
__global__ __launch_bounds__(256) void softmax_rows(u16* __restrict__ S) {
  const int t = threadIdx.x;
  u16* row = S + (long)blockIdx.x * 1056;
  float v[5];
  float mx = -1e30f;
#pragma unroll
  for (int i = 0; i < 5; ++i) {
    int c = t + i * 256;
    float x = (c < 1025) ? bf2f(row[c]) : -1e30f;
    v[i] = x; mx = fmaxf(mx, x);
  }
  __shared__ float red[4];
  __shared__ float red2[4];
  for (int o = 32; o > 0; o >>= 1) mx = fmaxf(mx, __shfl_xor(mx, o, 64));
  if ((t & 63) == 0) red[t >> 6] = mx;
  __syncthreads();
  mx = fmaxf(fmaxf(red[0], red[1]), fmaxf(red[2], red[3]));
  float s = 0.f;
#pragma unroll
  for (int i = 0; i < 5; ++i) {
    int c = t + i * 256;
    float e = (c < 1025) ? __expf(v[i] - mx) : 0.f;
    v[i] = e; s += e;
  }
  for (int o = 32; o > 0; o >>= 1) s += __shfl_xor(s, o, 64);
  if ((t & 63) == 0) red2[t >> 6] = s;
  __syncthreads();
  s = red2[0] + red2[1] + red2[2] + red2[3];
  float inv = 1.0f / s;
#pragma unroll
  for (int i = 0; i < 5; ++i) {
    int c = t + i * 256;
    if (c < 1056) row[c] = f2bf(v[i] * inv);
  }
}

// ---------------------------------------------------------------------------
// GEMM-BT: C[m][n] = sum_k A[m][k] * B[n][k]  (both K-contiguous bf16).
// Modes:
//  0 QKV   : A=xb(4100x512)        B=W(4096x512)   -> T[bn][l][c] bf16 (+bias)
//  1 POOL  : A=Q/K spatial-mapped  B=Wp(512x512)   -> P[bn][1+sp][c] (+bias,+emb?)
//  2 POOLT : A=V  spatial-mapped   B=Wp(512x512)   -> PVt[bn][c][1+sp] (+bias)
//  3 S     : A=PQ[gbz] B=PK[gbz] (1025x512)        -> Schunk[z][q][kv]*scale
//  4 O     : A=Schunk[z](1025x1056) B=PVt[gbz](512x1056)-> stacked (+Q resid)
//  5 FINAL : A=stacked(4100x4096) B=Wd(512x4096)   -> out f32 (+bias)
// ---------------------------------------------------------------------------
template <int MODE>
__global__ __launch_bounds__(256)
void gemm_bt(const u16* __restrict__ Ap, const u16* __restrict__ Bp,
             const float* __restrict__ bias, const float* __restrict__ emb,
             const u16* __restrict__ resid, u16* __restrict__ outb,
             float* __restrict__ outf, int bz0) {
  constexpr int K = (MODE == 5) ? 4096 : ((MODE == 4) ? 1056 : 512);
  __shared__ u16 As[128 * 32];
  __shared__ u16 Bs[128 * 32];
  const int tid = threadIdx.x;
  const int lane = tid & 63;
  const int wv = tid >> 6;
  const int wr = wv >> 1, wc = wv & 1;
  const int mt = blockIdx.y, nt = blockIdx.x;
  const int bz = blockIdx.z;           // local (chunk) z
  const int gbz = bz0 + bz;            // global (b*8+n)

  long a_row[2], b_row[2];
  int kcol[2];
#pragma unroll
  for (int c = 0; c < 2; ++c) {
    int idx = c * 256 + tid;
    int row = idx >> 2, kc = idx & 3;
    kcol[c] = kc * 8;
    {
      int r = mt * 128 + row;
      long off;
      if constexpr (MODE == 0) { r = r < 4099 ? r : 4099; off = (long)r * 512; }
      else if constexpr (MODE == 1 || MODE == 2) {
        off = ((long)(r >> 10) * 1025 + 1 + (r & 1023)) * 512;
      } else if constexpr (MODE == 3) { r = r < 1024 ? r : 1024; off = (long)gbz * 1025 * 512 + (long)r * 512; }
      else if constexpr (MODE == 4) { r = r < 1024 ? r : 1024; off = (long)bz * 1025 * 1056 + (long)r * 1056; }
      else { r = r < 4099 ? r : 4099; off = (long)r * 4096; }
      a_row[c] = off;
    }
    {
      int r = nt * 128 + row;
      long off;
      if constexpr (MODE == 0) off = (long)r * 512;
      else if constexpr (MODE == 1 || MODE == 2) off = (long)r * 512;
      else if constexpr (MODE == 3) { r = r < 1024 ? r : 1024; off = (long)gbz * 1025 * 512 + (long)r * 512; }
      else if constexpr (MODE == 4) off = (long)gbz * 512 * 1056 + (long)r * 1056;
      else off = (long)r * 4096;
      b_row[c] = off;
    }
  }

  floatx4 acc[4][4];
#pragma unroll
  for (int i = 0; i < 4; ++i)
#pragma unroll
    for (int j = 0; j < 4; ++j) acc[i][j] = floatx4{0.f, 0.f, 0.f, 0.f};

  const int lb0 = (wv * 64) * 16;          // wave-uniform LDS byte base, chunk 0
  const int lb1 = (256 + wv * 64) * 16;    // chunk 1

  for (int kt = 0; kt < K / 32; ++kt) {
    const int k0 = kt * 32;
    gld_lds16(Ap + a_row[0] + k0 + kcol[0], (char*)As + lb0);
    gld_lds16(Ap + a_row[1] + k0 + kcol[1], (char*)As + lb1);
    gld_lds16(Bp + b_row[0] + k0 + kcol[0], (char*)Bs + lb0);
    gld_lds16(Bp + b_row[1] + k0 + kcol[1], (char*)Bs + lb1);
    __syncthreads();
    short8 af[4], bf[4];
#pragma unroll
    for (int i = 0; i < 4; ++i)
      af[i] = *(const short8*)(As + (wr * 64 + i * 16 + (lane & 15)) * 32 + (lane >> 4) * 8);
#pragma unroll
    for (int j = 0; j < 4; ++j)
      bf[j] = *(const short8*)(Bs + (wc * 64 + j * 16 + (lane & 15)) * 32 + (lane >> 4) * 8);
#pragma unroll
    for (int i = 0; i < 4; ++i)
#pragma unroll
      for (int j = 0; j < 4; ++j)
        acc[i][j] = __builtin_amdgcn_mfma_f32_16x16x32_bf16(af[i], bf[j], acc[i][j], 0, 0, 0);
    __syncthreads();
  }

  // Epilogue: C/D layout col = lane&15, row = (lane>>4)*4 + reg.
  const int ccol = lane & 15;
  const int rgrp = lane >> 4;
#pragma unroll
  for (int i = 0; i < 4; ++i) {
#pragma unroll
    for (int j = 0; j < 4; ++j) {
      const int gcol = nt * 128 + wc * 64 + j * 16 + ccol;
#pragma unroll
      for (int rr = 0; rr < 4; ++rr) {
        const int grow = mt * 128 + wr * 64 + i * 16 + rgrp * 4 + rr;
        float v = acc[i][j][rr];
        if constexpr (MODE == 0) {
          if (grow < 4100) {
            v += bias[gcol];
            int b = grow / 1025;
            int l = grow - b * 1025;
            int n = gcol >> 9, ch = gcol & 511;
            outb[((long)(b * 8 + n) * 1025 + l) * 512 + ch] = f2bf(v);
          }
        } else if constexpr (MODE == 1) {
          int bn = grow >> 10, sp = grow & 1023;
          v += bias[gcol];
          if (emb) v += emb[sp * 512 + gcol];
          outb[((long)bn * 1025 + 1 + sp) * 512 + gcol] = f2bf(v);
        } else if constexpr (MODE == 2) {
          int bn = grow >> 10, sp = grow & 1023;
          v += bias[gcol];
          outb[((long)bn * 512 + gcol) * 1056 + 1 + sp] = f2bf(v);
        } else if constexpr (MODE == 3) {
          if (grow < 1025 && gcol < 1025)
            outb[((long)bz * 1025 + grow) * 1056 + gcol] = f2bf(v * 0.04419417382415922f);
        } else if constexpr (MODE == 4) {
          if (grow < 1025) {
            if (grow >= 1) v += bf2f(resid[((long)gbz * 1025 + grow) * 512 + gcol]);
            int b = gbz >> 3, n = gbz & 7;
            outb[(((long)b * 1025 + grow) * 8 + n) * 512 + gcol] = f2bf(v);
          }
        } else {
          if (grow < 4100) outf[(long)grow * 512 + gcol] = v + bias[gcol];
        }
      }
    }
  }
}

// ---------------------------------------------------------------------------
extern "C" void kernel_launch(void* const* d_in, const int* in_sizes, int n_in,
                              void* d_out, int out_size, void* d_ws, size_t ws_size,
                              hipStream_t stream) {
  const float* x   = (const float*)d_in[0];
  const float* Wq  = (const float*)d_in[1];
  const float* bq  = (const float*)d_in[2];
  const float* Wk  = (const float*)d_in[3];
  const float* bk  = (const float*)d_in[4];
  const float* Wv  = (const float*)d_in[5];
  const float* bv  = (const float*)d_in[6];
  const float* Wpq = (const float*)d_in[7];
  const float* bpq = (const float*)d_in[8];
  const float* Wpk = (const float*)d_in[9];
  const float* bpk = (const float*)d_in[10];
  const float* Wpv = (const float*)d_in[11];
  const float* bpv = (const float*)d_in[12];
  const float* Wd  = (const float*)d_in[13];
  const float* bd  = (const float*)d_in[14];
  float* out = (float*)d_out;

  char* ws = (char*)d_ws;
  size_t off = 0;
  auto alloc = [&](size_t bytes) {
    char* p = ws + off;
    off += (bytes + 255) & ~(size_t)255;
    return p;
  };
  u16* xb    = (u16*)alloc(4100ull * 512 * 2);
  u16* Wqb   = (u16*)alloc(4096ull * 512 * 2);
  u16* Wkb   = (u16*)alloc(4096ull * 512 * 2);
  u16* Wvb   = (u16*)alloc(4096ull * 512 * 2);
  u16* Wpqb  = (u16*)alloc(512ull * 512 * 2);
  u16* Wpkb  = (u16*)alloc(512ull * 512 * 2);
  u16* Wpvb  = (u16*)alloc(512ull * 512 * 2);
  u16* Wdb   = (u16*)alloc(512ull * 4096 * 2);
  float* embp = (float*)alloc(1024ull * 512 * 4);
  u16* Q     = (u16*)alloc(32ull * 1025 * 512 * 2);
  u16* KV    = (u16*)alloc(32ull * 1025 * 512 * 2);   // K, then V, then stk (alias)
  u16* PQ    = (u16*)alloc(32ull * 1025 * 512 * 2);
  u16* PK    = (u16*)alloc(32ull * 1025 * 512 * 2);
  u16* PVt   = (u16*)alloc(32ull * 512 * 1056 * 2);
  u16* S     = (u16*)alloc(8ull * 1025 * 1056 * 2);   // per-chunk (8 heads)
  u16* stk   = KV;  // 4100*4096*2 == 32*1025*512*2 (exactly equal); V dead by then
  (void)in_sizes; (void)n_in; (void)out_size;

  if (ws_size < off) return;  // clean fail (absmax ~0.45) instead of GPU fault

  // 1) dtype conversions (one launch)
  CvtArgs ca;
  ca.src[0] = x;   ca.dst[0] = xb;   ca.n4[0] = 4100 * 512 / 4;
  ca.src[1] = Wq;  ca.dst[1] = Wqb;  ca.n4[1] = 4096 * 512 / 4;
  ca.src[2] = Wk;  ca.dst[2] = Wkb;  ca.n4[2] = 4096 * 512 / 4;
  ca.src[3] = Wv;  ca.dst[3] = Wvb;  ca.n4[3] = 4096 * 512 / 4;
  ca.src[4] = Wpq; ca.dst[4] = Wpqb; ca.n4[4] = 512 * 512 / 4;
  ca.src[5] = Wpk; ca.dst[5] = Wpkb; ca.n4[5] = 512 * 512 / 4;
  ca.src[6] = Wpv; ca.dst[6] = Wpvb; ca.n4[6] = 512 * 512 / 4;
  ca.src[7] = Wd;  ca.dst[7] = Wdb;  ca.n4[7] = 512 * 4096 / 4;
  int total4 = 0;
  for (int s = 0; s < 8; ++s) total4 += ca.n4[s];
  cvt_all<<<(total4 + 255) / 256, 256, 0, stream>>>(ca, total4);

  // 2) positional embedding
  emb_kernel<<<(1024 * 512) / 256, 256, 0, stream>>>(embp);

  // 3) Q and K projections
  gemm_bt<0><<<dim3(32, 33, 1), 256, 0, stream>>>(xb, Wqb, bq, nullptr, nullptr, Q, nullptr, 0);
  gemm_bt<0><<<dim3(32, 33, 1), 256, 0, stream>>>(xb, Wkb, bk, nullptr, nullptr, KV, nullptr, 0);

  // 4) cls passthrough for PQ/PK
  cls_qk<<<(32 * 512) / 256, 256, 0, stream>>>(Q, KV, PQ, PK);

  // 5) pools for Q (with pos-embed) and K
  gemm_bt<1><<<dim3(4, 256, 1), 256, 0, stream>>>(Q, Wpqb, bpq, embp, nullptr, PQ, nullptr, 0);
  gemm_bt<1><<<dim3(4, 256, 1), 256, 0, stream>>>(KV, Wpkb, bpk, nullptr, nullptr, PK, nullptr, 0);

  // 6) V projection (reuse KV buffer), cls, pool (transposed output)
  gemm_bt<0><<<dim3(32, 33, 1), 256, 0, stream>>>(xb, Wvb, bv, nullptr, nullptr, KV, nullptr, 0);
  cls_v<<<(32 * 512) / 256, 256, 0, stream>>>(KV, PVt);
  gemm_bt<2><<<dim3(4, 256, 1), 256, 0, stream>>>(KV, Wpvb, bpv, nullptr, nullptr, PVt, nullptr, 0);
  // KV (V) is now dead -> stk may alias it.

  // 7) attention in 4 chunks of 8 heads: logits -> softmax -> O (+Q resid)
  for (int c = 0; c < 4; ++c) {
    int bz0 = c * 8;
    gemm_bt<3><<<dim3(9, 9, 8), 256, 0, stream>>>(PQ, PK, nullptr, nullptr, nullptr, S, nullptr, bz0);
    softmax_rows<<<8 * 1025, 256, 0, stream>>>(S);
    gemm_bt<4><<<dim3(4, 9, 8), 256, 0, stream>>>(S, PVt, nullptr, nullptr, Q, stk, nullptr, bz0);
  }

  // 8) final projection -> f32 out
  gemm_bt<5><<<dim3(4, 33, 1), 256, 0, stream>>>(stk, Wdb, bd, nullptr, nullptr, nullptr, out, 0);
}

// Round 4
// 665.651 us; speedup vs baseline: 1.2214x; 1.2214x over previous
//
#include <hip/hip_runtime.h>

// ---------------------------------------------------------------------------
// MultiHeadPooledSelfAttention on gfx950.
// bf16 cast once -> all matmul stages through one m97-style GEMM-BT kernel
// (128x128 tile, BK=32, global_load_lds width=16, mfma_f32_16x16x32_bf16,
// 4x4 acc/wave). R3: adaptive attention chunking (S aliases dead early
// buffers), split-K x4 final projection (partials alias dead PQ), merged
// Q+K projection, vectorized softmax.
// ---------------------------------------------------------------------------

typedef unsigned short u16;
typedef __attribute__((ext_vector_type(8))) short short8;   // 8 x bf16
typedef __attribute__((ext_vector_type(4))) float floatx4;
typedef __attribute__((ext_vector_type(4))) unsigned short us4;

__device__ __forceinline__ u16 f2bf(float f) {
  union { float f; unsigned u; } x; x.f = f;
  unsigned r = (x.u + 0x7fffu + ((x.u >> 16) & 1u)) >> 16;
  return (u16)r;
}
__device__ __forceinline__ float bf2f(u16 u) {
  union { unsigned u; float f; } x; x.u = ((unsigned)u) << 16;
  return x.f;
}

__device__ __forceinline__ void gld_lds16(const void* g, void* l) {
  __builtin_amdgcn_global_load_lds(
      (const __attribute__((address_space(1))) void*)g,
      (__attribute__((address_space(3))) void*)l, 16, 0, 0);
}

// ---------------------------------------------------------------------------
struct CvtArgs { const float* src[8]; u16* dst[8]; int n4[8]; };

__global__ __launch_bounds__(256) void cvt_all(CvtArgs a, int total4) {
  int t = blockIdx.x * 256 + threadIdx.x;
  if (t >= total4) return;
#pragma unroll
  for (int s = 0; s < 8; ++s) {
    if (t < a.n4[s]) {
      const float* sp = a.src[s] + (long)t * 4;
      u16* dp = a.dst[s] + (long)t * 4;
      float4 v = *(const float4*)sp;
      dp[0] = f2bf(v.x); dp[1] = f2bf(v.y); dp[2] = f2bf(v.z); dp[3] = f2bf(v.w);
      return;
    }
    t -= a.n4[s];
  }
}

// ---------------------------------------------------------------------------
__global__ __launch_bounds__(256) void emb_kernel(float* __restrict__ e) {
  int t = blockIdx.x * 256 + threadIdx.x;    // < 1024*512
  int c = t & 511, sp = t >> 9;
  int y = sp >> 5, xg = sp & 31;
  int j = c & 127, seg = c >> 7;
  float omega = expf(-(float)j * (9.210340371976184f / 128.f));  // 10000^{-j/128}
  float arg = (float)((seg < 2) ? y : xg) * omega;
  e[t] = (seg & 1) ? cosf(arg) : sinf(arg);
}

// ---------------------------------------------------------------------------
__global__ __launch_bounds__(256) void cls_qk(const u16* __restrict__ Q, const u16* __restrict__ K,
                                              u16* __restrict__ PQ, u16* __restrict__ PK) {
  int t = blockIdx.x * 256 + threadIdx.x;    // < 32*512
  int bn = t >> 9, c = t & 511;
  long o = (long)bn * 1025 * 512 + c;
  PQ[o] = Q[o];
  PK[o] = K[o];
}
__global__ __launch_bounds__(256) void cls_v(const u16* __restrict__ V, u16* __restrict__ PVt) {
  int t = blockIdx.x * 256 + threadIdx.x;
  int bn = t >> 9, c = t & 511;
  PVt[((long)bn * 512 + c) * 1056] = V[(long)bn * 1025 * 512 + c];
}

// ---------------------------------------------------------------------------
// Softmax: one block per row (heads*1025 rows, 1056 cols, valid 1025).
// Vectorized us4 loads/stores; zero-fills pad cols 1025..1055.
// ---------------------------------------------------------------------------
__global__ __launch_bounds__(256) void softmax_rows(u16* __restrict__ S) {
  const int t = threadIdx.x;
  u16* row = S + (long)blockIdx.x * 1056;
  us4 p = *(const us4*)(row + t * 4);       // elements 4t..4t+3, all < 1024
  float v[4];
  float mx = -1e30f;
#pragma unroll
  for (int i = 0; i < 4; ++i) { v[i] = bf2f(p[i]); mx = fmaxf(mx, v[i]); }
  float e1024 = (t == 0) ? bf2f(row[1024]) : -1e30f;
  mx = fmaxf(mx, e1024);
  __shared__ float red[4], red2[4];
  for (int o = 32; o > 0; o >>= 1) mx = fmaxf(mx, __shfl_xor(mx, o, 64));
  if ((t & 63) == 0) red[t >> 6] = mx;
  __syncthreads();
  mx = fmaxf(fmaxf(red[0], red[1]), fmaxf(red[2], red[3]));
  float s = 0.f;
#pragma unroll
  for (int i = 0; i < 4; ++i) { v[i] = __expf(v[i] - mx); s += v[i]; }
  e1024 = (t == 0) ? __expf(e1024 - mx) : 0.f;
  s += e1024;
  for (int o = 32; o > 0; o >>= 1) s += __shfl_xor(s, o, 64);
  if ((t & 63) == 0) red2[t >> 6] = s;
  __syncthreads();
  s = red2[0] + red2[1] + red2[2] + red2[3];
  float inv = 1.0f / s;
#pragma unroll
  for (int i = 0; i < 4; ++i) p[i] = f2bf(v[i] * inv);
  *(us4*)(row + t * 4) = p;
  if (t < 8) {                               // elements 1024..1055
    us4 q;
#pragma unroll
    for (int i = 0; i < 4; ++i) q[i] = 0;
    if (t == 0) q[0] = f2bf(e1024 * inv);
    *(us4*)(row + 1024 + t * 4) = q;
  }
}

// ---------------------------------------------------------------------------
// Final reduce for split-K projection: out = sum_z part[z] + bias.
// ---------------------------------------------------------------------------
__global__ __launch_bounds__(256) void reduce4(const float* __restrict__ part,
                                               const float* __restrict__ bd,
                                               float* __restrict__ out) {
  int t = blockIdx.x * 256 + threadIdx.x;    // < 524800
  long i = (long)t * 4;
  const long STR = 4100ll * 512;
  float4 a = *(const float4*)(part + i);
  float4 b = *(const float4*)(part + i + STR);
  float4 c = *(const float4*)(part + i + 2 * STR);
  float4 d = *(const float4*)(part + i + 3 * STR);
  float4 bb = *(const float4*)(bd + (int)(i & 511));
  float4 r;
  r.x = a.x + b.x + c.x + d.x + bb.x;
  r.y = a.y + b.y + c.y + d.y + bb.y;
  r.z = a.z + b.z + c.z + d.z + bb.z;
  r.w = a.w + b.w + c.w + d.w + bb.w;
  *(float4*)(out + i) = r;
}

// ---------------------------------------------------------------------------
// GEMM-BT: C[m][n] = sum_k A[m][k] * B[n][k]  (both K-contiguous bf16).
// Modes:
//  0 QKV   : A=xb(4100x512)  B=W(Nx512, N=4096 or 8192 merged) -> T[bn][l][c]
//            (+bias); outb2/bias2 for gcol>=4096 (merged Q+K)
//  1 POOL  : A=Q/K spatial-mapped  B=Wp(512x512) -> P[bn][1+sp][c] (+bias,+emb?)
//  2 POOLT : A=V  spatial-mapped   B=Wp(512x512) -> PVt[bn][c][1+sp] (+bias)
//  3 S     : A=PQ[gbz] B=PK[gbz] (1025x512)      -> Schunk[z][q][kv]*scale
//  4 O     : A=Schunk[z](1025x1056) B=PVt[gbz](512x1056) -> stacked (+Q resid)
//  5 FINAL : A=stacked(4100x4096) B=Wd(512x4096), split-K x4 over z
//            -> f32 partials [z][row][col] (bias added in reduce4)
// ---------------------------------------------------------------------------
template <int MODE>
__global__ __launch_bounds__(256)
void gemm_bt(const u16* __restrict__ Ap, const u16* __restrict__ Bp,
             const float* __restrict__ bias, const float* __restrict__ bias2,
             const float* __restrict__ emb, const u16* __restrict__ resid,
             u16* __restrict__ outb, u16* __restrict__ outb2,
             float* __restrict__ outf, int bz0) {
  constexpr int KITER = (MODE == 5) ? 32 : ((MODE == 4) ? 33 : 16);
  __shared__ u16 As[128 * 32];
  __shared__ u16 Bs[128 * 32];
  const int tid = threadIdx.x;
  const int lane = tid & 63;
  const int wv = tid >> 6;
  const int wr = wv >> 1, wc = wv & 1;
  const int mt = blockIdx.y, nt = blockIdx.x;
  const int bz = blockIdx.z;           // local z (chunk index / k-split index)
  const int gbz = bz0 + bz;            // global (b*8+n)

  long a_row[2], b_row[2];
  int kcol[2];
#pragma unroll
  for (int c = 0; c < 2; ++c) {
    int idx = c * 256 + tid;
    int row = idx >> 2, kc = idx & 3;
    kcol[c] = kc * 8;
    {
      int r = mt * 128 + row;
      long off;
      if constexpr (MODE == 0) { r = r < 4099 ? r : 4099; off = (long)r * 512; }
      else if constexpr (MODE == 1 || MODE == 2) {
        off = ((long)(r >> 10) * 1025 + 1 + (r & 1023)) * 512;
      } else if constexpr (MODE == 3) { r = r < 1024 ? r : 1024; off = (long)gbz * 1025 * 512 + (long)r * 512; }
      else if constexpr (MODE == 4) { r = r < 1024 ? r : 1024; off = (long)bz * 1025 * 1056 + (long)r * 1056; }
      else { r = r < 4099 ? r : 4099; off = (long)r * 4096; }
      a_row[c] = off;
    }
    {
      int r = nt * 128 + row;
      long off;
      if constexpr (MODE == 0) off = (long)r * 512;
      else if constexpr (MODE == 1 || MODE == 2) off = (long)r * 512;
      else if constexpr (MODE == 3) { r = r < 1024 ? r : 1024; off = (long)gbz * 1025 * 512 + (long)r * 512; }
      else if constexpr (MODE == 4) off = (long)gbz * 512 * 1056 + (long)r * 1056;
      else off = (long)r * 4096;
      b_row[c] = off;
    }
  }

  floatx4 acc[4][4];
#pragma unroll
  for (int i = 0; i < 4; ++i)
#pragma unroll
    for (int j = 0; j < 4; ++j) acc[i][j] = floatx4{0.f, 0.f, 0.f, 0.f};

  const int lb0 = (wv * 64) * 16;          // wave-uniform LDS byte base, chunk 0
  const int lb1 = (256 + wv * 64) * 16;    // chunk 1
  const int kbase = (MODE == 5) ? bz * 1024 : 0;

  for (int kt = 0; kt < KITER; ++kt) {
    const int k0 = kbase + kt * 32;
    gld_lds16(Ap + a_row[0] + k0 + kcol[0], (char*)As + lb0);
    gld_lds16(Ap + a_row[1] + k0 + kcol[1], (char*)As + lb1);
    gld_lds16(Bp + b_row[0] + k0 + kcol[0], (char*)Bs + lb0);
    gld_lds16(Bp + b_row[1] + k0 + kcol[1], (char*)Bs + lb1);
    __syncthreads();
    short8 af[4], bf[4];
#pragma unroll
    for (int i = 0; i < 4; ++i)
      af[i] = *(const short8*)(As + (wr * 64 + i * 16 + (lane & 15)) * 32 + (lane >> 4) * 8);
#pragma unroll
    for (int j = 0; j < 4; ++j)
      bf[j] = *(const short8*)(Bs + (wc * 64 + j * 16 + (lane & 15)) * 32 + (lane >> 4) * 8);
#pragma unroll
    for (int i = 0; i < 4; ++i)
#pragma unroll
      for (int j = 0; j < 4; ++j)
        acc[i][j] = __builtin_amdgcn_mfma_f32_16x16x32_bf16(af[i], bf[j], acc[i][j], 0, 0, 0);
    __syncthreads();
  }

  // Epilogue: C/D layout col = lane&15, row = (lane>>4)*4 + reg.
  const int ccol = lane & 15;
  const int rgrp = lane >> 4;
#pragma unroll
  for (int i = 0; i < 4; ++i) {
#pragma unroll
    for (int j = 0; j < 4; ++j) {
      const int gcol = nt * 128 + wc * 64 + j * 16 + ccol;
#pragma unroll
      for (int rr = 0; rr < 4; ++rr) {
        const int grow = mt * 128 + wr * 64 + i * 16 + rgrp * 4 + rr;
        float v = acc[i][j][rr];
        if constexpr (MODE == 0) {
          if (grow < 4100) {
            int col = gcol;
            u16* ob = outb;
            const float* bs = bias;
            if (outb2 != nullptr && gcol >= 4096) { col = gcol - 4096; ob = outb2; bs = bias2; }
            float vv = v + bs[col];
            int b = grow / 1025;
            int l = grow - b * 1025;
            int n = col >> 9, ch = col & 511;
            ob[((long)(b * 8 + n) * 1025 + l) * 512 + ch] = f2bf(vv);
          }
        } else if constexpr (MODE == 1) {
          int bn = grow >> 10, sp = grow & 1023;
          v += bias[gcol];
          if (emb) v += emb[sp * 512 + gcol];
          outb[((long)bn * 1025 + 1 + sp) * 512 + gcol] = f2bf(v);
        } else if constexpr (MODE == 2) {
          int bn = grow >> 10, sp = grow & 1023;
          v += bias[gcol];
          outb[((long)bn * 512 + gcol) * 1056 + 1 + sp] = f2bf(v);
        } else if constexpr (MODE == 3) {
          if (grow < 1025 && gcol < 1025)
            outb[((long)bz * 1025 + grow) * 1056 + gcol] = f2bf(v * 0.04419417382415922f);
        } else if constexpr (MODE == 4) {
          if (grow < 1025) {
            if (grow >= 1) v += bf2f(resid[((long)gbz * 1025 + grow) * 512 + gcol]);
            int b = gbz >> 3, n = gbz & 7;
            outb[(((long)b * 1025 + grow) * 8 + n) * 512 + gcol] = f2bf(v);
          }
        } else {
          if (grow < 4100)
            outf[((long)bz * 4100 + grow) * 512 + gcol] = v;   // partial, no bias
        }
      }
    }
  }
}

// ---------------------------------------------------------------------------
extern "C" void kernel_launch(void* const* d_in, const int* in_sizes, int n_in,
                              void* d_out, int out_size, void* d_ws, size_t ws_size,
                              hipStream_t stream) {
  const float* x   = (const float*)d_in[0];
  const float* Wq  = (const float*)d_in[1];
  const float* bq  = (const float*)d_in[2];
  const float* Wk  = (const float*)d_in[3];
  const float* bk  = (const float*)d_in[4];
  const float* Wv  = (const float*)d_in[5];
  const float* bv  = (const float*)d_in[6];
  const float* Wpq = (const float*)d_in[7];
  const float* bpq = (const float*)d_in[8];
  const float* Wpk = (const float*)d_in[9];
  const float* bpk = (const float*)d_in[10];
  const float* Wpv = (const float*)d_in[11];
  const float* bpv = (const float*)d_in[12];
  const float* Wd  = (const float*)d_in[13];
  const float* bd  = (const float*)d_in[14];
  float* out = (float*)d_out;

  char* ws = (char*)d_ws;
  size_t off = 0;
  auto alloc = [&](size_t bytes) {
    char* p = ws + off;
    off += (bytes + 255) & ~(size_t)255;
    return p;
  };
  // Persistent-through-attention group first:
  u16* Wpqb  = (u16*)alloc(512ull * 512 * 2);
  u16* Wpkb  = (u16*)alloc(512ull * 512 * 2);
  u16* Wpvb  = (u16*)alloc(512ull * 512 * 2);
  u16* Wdb   = (u16*)alloc(512ull * 4096 * 2);
  u16* Q     = (u16*)alloc(32ull * 1025 * 512 * 2);
  u16* KV    = (u16*)alloc(32ull * 1025 * 512 * 2);   // K -> V -> stk (alias)
  u16* PQ    = (u16*)alloc(32ull * 1025 * 512 * 2);   // later: f32 partials (same size)
  u16* PK    = (u16*)alloc(32ull * 1025 * 512 * 2);
  u16* PVt   = (u16*)alloc(32ull * 512 * 1056 * 2);
  // Dead-by-attention-time group (S aliases from here):
  size_t s_off = off;
  u16* xb    = (u16*)alloc(4100ull * 512 * 2);
  u16* Wqb   = (u16*)alloc(4096ull * 512 * 2);   // contiguous with Wkb (merged QK)
  u16* Wkb   = (u16*)alloc(4096ull * 512 * 2);
  u16* Wvb   = (u16*)alloc(4096ull * 512 * 2);
  float* embp = (float*)alloc(1024ull * 512 * 4);
  size_t fixed_need = off;
  u16* S    = (u16*)(ws + s_off);
  u16* stk  = KV;                       // V dead before stk written
  float* part = (float*)PQ;             // PQ dead before partials written
  (void)in_sizes; (void)n_in; (void)out_size;

  // Adaptive attention chunking: pick the fewest chunks that fit ws_size.
  const size_t srow = 1056ull * 2;
  size_t need1 = s_off + 32ull * 1025 * srow;   // ~244 MB
  size_t need2 = s_off + 16ull * 1025 * srow;   // ~209 MB
  size_t need4 = fixed_need;                    // ~194 MB (S8 fits in dead group)
  int nchunk = (ws_size >= need1) ? 1 : (ws_size >= need2) ? 2 : 4;
  if (ws_size < need4) return;   // clean fail instead of GPU fault
  int hpc = 32 / nchunk;         // heads per chunk

  // 1) dtype conversions (one launch)
  CvtArgs ca;
  ca.src[0] = x;   ca.dst[0] = xb;   ca.n4[0] = 4100 * 512 / 4;
  ca.src[1] = Wq;  ca.dst[1] = Wqb;  ca.n4[1] = 4096 * 512 / 4;
  ca.src[2] = Wk;  ca.dst[2] = Wkb;  ca.n4[2] = 4096 * 512 / 4;
  ca.src[3] = Wv;  ca.dst[3] = Wvb;  ca.n4[3] = 4096 * 512 / 4;
  ca.src[4] = Wpq; ca.dst[4] = Wpqb; ca.n4[4] = 512 * 512 / 4;
  ca.src[5] = Wpk; ca.dst[5] = Wpkb; ca.n4[5] = 512 * 512 / 4;
  ca.src[6] = Wpv; ca.dst[6] = Wpvb; ca.n4[6] = 512 * 512 / 4;
  ca.src[7] = Wd;  ca.dst[7] = Wdb;  ca.n4[7] = 512 * 4096 / 4;
  int total4 = 0;
  for (int s = 0; s < 8; ++s) total4 += ca.n4[s];
  cvt_all<<<(total4 + 255) / 256, 256, 0, stream>>>(ca, total4);

  // 2) positional embedding
  emb_kernel<<<(1024 * 512) / 256, 256, 0, stream>>>(embp);

  // 3) merged Q+K projection (Wqb||Wkb contiguous, N=8192)
  gemm_bt<0><<<dim3(64, 33, 1), 256, 0, stream>>>(xb, Wqb, bq, bk, nullptr, nullptr, Q, KV, nullptr, 0);

  // 4) cls passthrough for PQ/PK
  cls_qk<<<(32 * 512) / 256, 256, 0, stream>>>(Q, KV, PQ, PK);

  // 5) pools for Q (with pos-embed) and K
  gemm_bt<1><<<dim3(4, 256, 1), 256, 0, stream>>>(Q, Wpqb, bpq, nullptr, embp, nullptr, PQ, nullptr, nullptr, 0);
  gemm_bt<1><<<dim3(4, 256, 1), 256, 0, stream>>>(KV, Wpkb, bpk, nullptr, nullptr, nullptr, PK, nullptr, nullptr, 0);

  // 6) V projection (reuse KV buffer), cls, pool (transposed output)
  gemm_bt<0><<<dim3(32, 33, 1), 256, 0, stream>>>(xb, Wvb, bv, nullptr, nullptr, nullptr, KV, nullptr, nullptr, 0);
  cls_v<<<(32 * 512) / 256, 256, 0, stream>>>(KV, PVt);
  gemm_bt<2><<<dim3(4, 256, 1), 256, 0, stream>>>(KV, Wpvb, bpv, nullptr, nullptr, nullptr, PVt, nullptr, nullptr, 0);
  // xb/Wqb/Wkb/Wvb/embp now dead -> S may alias; KV (V) dead -> stk aliases.

  // 7) attention in nchunk chunks: logits -> softmax -> O (+Q resid)
  for (int c = 0; c < nchunk; ++c) {
    int bz0 = c * hpc;
    gemm_bt<3><<<dim3(9, 9, hpc), 256, 0, stream>>>(PQ, PK, nullptr, nullptr, nullptr, nullptr, S, nullptr, nullptr, bz0);
    softmax_rows<<<hpc * 1025, 256, 0, stream>>>(S);
    gemm_bt<4><<<dim3(4, 9, hpc), 256, 0, stream>>>(S, PVt, nullptr, nullptr, nullptr, Q, stk, nullptr, nullptr, bz0);
  }
  // PQ now dead -> f32 partials alias it.

  // 8) final projection, split-K x4 -> partials, then reduce (+bias)
  gemm_bt<5><<<dim3(4, 33, 4), 256, 0, stream>>>(stk, Wdb, nullptr, nullptr, nullptr, nullptr, nullptr, nullptr, part, 0);
  reduce4<<<(4100 * 512 / 4 + 255) / 256, 256, 0, stream>>>(part, bd, out);
}